// Round 11
// baseline (317.863 us; speedup 1.0000x reference)
//
#include <hip/hip_runtime.h>
#include <math.h>

#define D 128
#define BSH 9        // bucket shift: 512 nodes/bucket
#define NPB 512      // nodes per bucket
#define SLOT 128     // slots per (bucket, bin-block): mean 64, 8-sigma headroom
#define STCAP 6252   // edges per bin block (mult of 4)
#define NBB 256      // bin blocks per graph
#define NBKT_MAX 128
#define SB 8         // sub-blocks per bucket in part passes
#define CPS (NBB / SB)   // bin-chunks per sub-block = 32

// ---------------------------------------------------------------------------
// Collapsed linear GCN (math unchanged):
//   u0 = 1/N,  u_{k+1}[s] = sum_{e: src_e=s} inv_deg[dst_e] * u_k[dst_e]
//   mean(h3) = r@W0W1W2 + s2*(b0@W1W2) + s1*(b1@W2) + b2,  r = u3^T feat
// MEASURED LESSONS:
//   R9-R11: kernel boundaries are the only cheap cross-XCD coherence.
//   R13: NEVER scatter-atomic at E scale; atomics on FEW addresses fine.
//   R14: ballot-ranking binning = VALU-bound. R15: 4B scatter = 7x write amp.
//   R16: per-kernel cost ~3x traffic roofline. R17: grid >= CUs always.
//   R18-R20: ILP/branch-free passes worth ~10us each.
//   R21: dense cursor bins REGRESSED +15us (unaligned run boundaries).
//   R22: gather-clamp + replicated histogram = null. Plateau 275-278;
//        no kernel BW- or compute-bound -> residual = launch/latency floor.
// R23 (this round): launch-count attack, formats untouched:
//   - wprep folded into bin_kernel (blockIdx.x==NBB slice, 4 blocks) ->
//     runs concurrent with binning, one less launch+gap.
//   - prop_combine at 784x128 (was 196x512): 4x blocks for the pure-
//     latency partial-sum kernel.
// ---------------------------------------------------------------------------

// Counting-sort binning, deterministic slots, one side per block.
//   side 0 (src): payload (src&511)<<17 | dst   (dst < 2^17)
//   side 1 (dst): payload ushort (dst&511)
// blockIdx.x == NBB: weight pre-collapse (T0=W1@W2 quarters, Av, Bv).
__global__ __launch_bounds__(512) void bin_kernel(
        const int* __restrict__ src_p, const int* __restrict__ dst_p,
        const int* __restrict__ src_s, const int* __restrict__ dst_s,
        int* __restrict__ sbins, unsigned short* __restrict__ dbins,
        unsigned* __restrict__ cnt_s, unsigned* __restrict__ cnt_d,
        const float* __restrict__ W1, const float* __restrict__ W2,
        const float* __restrict__ b0, const float* __restrict__ b1,
        float* __restrict__ T0, float* __restrict__ Av, float* __restrict__ Bv,
        int E, int nbkt) {
    const int b = blockIdx.x, side = blockIdx.y, g = blockIdx.z;
    const int tid = threadIdx.x;

    __shared__ int stage[STCAP];            // side1 aliases as ushort
    __shared__ unsigned hist4[4][NBKT_MAX];
    __shared__ unsigned hist[NBKT_MAX], offs[NBKT_MAX], lcur[NBKT_MAX];

    if (b == NBB) {
        // wprep slice: 4 blocks, quarter qi = side*2+g.
        const int qi = side * 2 + g;
        for (int i = tid; i < 4096; i += 512) {
            int row = 32 * qi + (i >> 7), col = i & 127;
            float acc = 0.f;
            const float* w1r = W1 + (size_t)row * 128;
            #pragma unroll 8
            for (int k = 0; k < 128; ++k) acc += w1r[k] * W2[(size_t)k * 128 + col];
            T0[(size_t)row * 128 + col] = acc;
        }
        if (qi == 2) {          // Bv = b1@W2
            if (tid < 128) {
                float a = 0.f;
                #pragma unroll 8
                for (int i = 0; i < 128; ++i) a += b1[i] * W2[(size_t)i * 128 + tid];
                Bv[tid] = a;
            }
        } else if (qi == 3) {   // Av = (b0@W1)@W2
            float* bv = (float*)hist;   // reuse 128-slot LDS
            if (tid < 128) {
                float a = 0.f;
                #pragma unroll 8
                for (int i = 0; i < 128; ++i) a += b0[i] * W1[(size_t)i * 128 + tid];
                bv[tid] = a;
            }
            __syncthreads();
            if (tid < 128) {
                float a = 0.f;
                #pragma unroll 8
                for (int i = 0; i < 128; ++i) a += bv[i] * W2[(size_t)i * 128 + tid];
                Av[tid] = a;
            }
        }
        return;
    }

    const int* src = g ? src_s : src_p;
    const int* dst = g ? dst_s : dst_p;
    const int* key = side ? dst : src;
    const int wv = tid >> 6, lane = tid & 63;
    const int rep = tid >> 7;               // 4 histogram replicas
    for (int i = tid; i < 4 * NBKT_MAX; i += 512) ((unsigned*)hist4)[i] = 0u;
    __syncthreads();

    const int e0 = b * STCAP;
    const int e1 = min(e0 + STCAP, E);
    const int efull = e0 + ((e1 - e0) & ~3);

    // phase 1: replicated histogram of keys
    for (int e = e0 + tid * 4; e + 4 <= e1; e += 512 * 4) {
        int4 k4 = *(const int4*)(key + e);
        atomicAdd(&hist4[rep][k4.x >> BSH], 1u);
        atomicAdd(&hist4[rep][k4.y >> BSH], 1u);
        atomicAdd(&hist4[rep][k4.z >> BSH], 1u);
        atomicAdd(&hist4[rep][k4.w >> BSH], 1u);
    }
    for (int e = efull + tid; e < e1; e += 512)
        atomicAdd(&hist4[rep][key[e] >> BSH], 1u);
    __syncthreads();
    if (tid < NBKT_MAX)
        hist[tid] = hist4[0][tid] + hist4[1][tid] + hist4[2][tid] + hist4[3][tid];
    __syncthreads();

    // wave 0: exclusive scan
    if (wv == 0) {
        unsigned a = (2 * lane < nbkt) ? hist[2 * lane] : 0u;
        unsigned bb = (2 * lane + 1 < nbkt) ? hist[2 * lane + 1] : 0u;
        unsigned v = a + bb;
        for (int d2 = 1; d2 < 64; d2 <<= 1) {
            unsigned t = __shfl_up(v, d2);
            if (lane >= d2) v += t;
        }
        unsigned ex = v - (a + bb);
        if (2 * lane < nbkt) { offs[2 * lane] = ex; lcur[2 * lane] = ex; }
        if (2 * lane + 1 < nbkt) { offs[2 * lane + 1] = ex + a; lcur[2 * lane + 1] = ex + a; }
    }
    __syncthreads();

    if (side == 0) {
        for (int e = e0 + tid * 4; e + 4 <= e1; e += 512 * 4) {
            int4 s4 = *(const int4*)(src + e);
            int4 d4 = *(const int4*)(dst + e);
            int sv[4] = {s4.x, s4.y, s4.z, s4.w};
            int dv[4] = {d4.x, d4.y, d4.z, d4.w};
            #pragma unroll
            for (int k = 0; k < 4; ++k) {
                unsigned p = atomicAdd(&lcur[sv[k] >> BSH], 1u);
                stage[p] = ((sv[k] & (NPB - 1)) << 17) | dv[k];
            }
        }
        for (int e = efull + tid; e < e1; e += 512) {
            int s = src[e], d2 = dst[e];
            unsigned p = atomicAdd(&lcur[s >> BSH], 1u);
            stage[p] = ((s & (NPB - 1)) << 17) | d2;
        }
        __syncthreads();
        int* sb = sbins + (size_t)g * nbkt * NBB * SLOT;
        unsigned* csp = cnt_s + (size_t)g * nbkt * NBB;
        for (int q = wv; q < nbkt; q += 8) {
            unsigned cs = min(hist[q], (unsigned)SLOT);
            unsigned os = offs[q];
            int* dp = sb + ((size_t)q * NBB + b) * SLOT;
            for (unsigned i = lane; i < cs; i += 64) dp[i] = stage[os + i];
            if (lane == 0) csp[q * NBB + b] = cs;
        }
    } else {
        unsigned short* st = (unsigned short*)stage;
        for (int e = e0 + tid * 4; e + 4 <= e1; e += 512 * 4) {
            int4 d4 = *(const int4*)(dst + e);
            int dv[4] = {d4.x, d4.y, d4.z, d4.w};
            #pragma unroll
            for (int k = 0; k < 4; ++k) {
                unsigned p = atomicAdd(&lcur[dv[k] >> BSH], 1u);
                st[p] = (unsigned short)(dv[k] & (NPB - 1));
            }
        }
        for (int e = efull + tid; e < e1; e += 512) {
            int d2 = dst[e];
            unsigned p = atomicAdd(&lcur[d2 >> BSH], 1u);
            st[p] = (unsigned short)(d2 & (NPB - 1));
        }
        __syncthreads();
        unsigned short* db = dbins + (size_t)g * nbkt * NBB * SLOT;
        unsigned* cdp = cnt_d + (size_t)g * nbkt * NBB;
        for (int q = wv; q < nbkt; q += 8) {
            unsigned cd = min(hist[q], (unsigned)SLOT);
            unsigned od = offs[q];
            unsigned short* ddp = db + ((size_t)q * NBB + b) * SLOT;
            for (unsigned i = lane; i < cd; i += 64) ddp[i] = st[od + i];
            if (lane == 0) cdp[q * NBB + b] = cd;
        }
    }
}

// deg partial: 256 thr, 4 replicas, unconditional loads, predicated atomics.
__global__ __launch_bounds__(256) void deg_part(
        const unsigned short* __restrict__ dbins, const unsigned* __restrict__ cnt_d,
        float* __restrict__ partials, int nbkt) {
    const int s = blockIdx.x, q = blockIdx.y, g = blockIdx.z;
    const unsigned short* dq = dbins + ((size_t)(g * nbkt + q) * NBB + s * CPS) * SLOT;
    const unsigned* cq = cnt_d + (size_t)(g * nbkt + q) * NBB + s * CPS;
    const int tid = threadIdx.x, wv = tid >> 6;
    __shared__ float bl[4][NPB];
    __shared__ unsigned lcnt[CPS];
    if (tid < CPS) lcnt[tid] = cq[tid];
    for (int i = tid; i < 4 * NPB; i += 256) ((float*)bl)[i] = 0.f;
    __syncthreads();
    float* mybl = bl[wv];
    const ushort4* d4 = (const ushort4*)dq;
    ushort4 v[4]; int limv[4];
    #pragma unroll
    for (int it = 0; it < 4; ++it) v[it] = d4[it * 256 + tid];      // unconditional
    #pragma unroll
    for (int it = 0; it < 4; ++it) {
        int i = it * 256 + tid;
        limv[it] = (int)lcnt[i >> 5] - ((i & 31) << 2);
    }
    #pragma unroll
    for (int it = 0; it < 4; ++it) {
        if (limv[it] > 0) atomicAdd(&mybl[v[it].x & 511], 1.f);
        if (limv[it] > 1) atomicAdd(&mybl[v[it].y & 511], 1.f);
        if (limv[it] > 2) atomicAdd(&mybl[v[it].z & 511], 1.f);
        if (limv[it] > 3) atomicAdd(&mybl[v[it].w & 511], 1.f);
    }
    __syncthreads();
    float* pp = partials + (((size_t)(g * nbkt + q)) * SB + s) * NPB;
    for (int i = tid; i < NPB; i += 256)
        pp[i] = bl[0][i] + bl[1][i] + bl[2][i] + bl[3][i];
}

// deg combine: inv = 1/max(deg,1); block (0,0) zeroes sums+fpart2.
__global__ __launch_bounds__(512) void deg_combine(
        const float* __restrict__ partials, float* __restrict__ inv,
        float* __restrict__ zbase, int zcount, int N, int nbkt) {
    const int q = blockIdx.x, g = blockIdx.y;
    const int tid = threadIdx.x;
    if (q == 0 && g == 0)
        for (int i = tid; i < zcount; i += 512) zbase[i] = 0.f;
    const float* pp = partials + ((size_t)(g * nbkt + q)) * SB * NPB;
    float t = 0.f;
    #pragma unroll
    for (int s = 0; s < SB; ++s) t += pp[s * NPB + tid];
    const int node = q * NPB + tid;
    if (node < N) inv[(size_t)g * N + node] = 1.0f / fmaxf(t, 1.0f);
}

// prop partial: unconditional slot loads, clamped gather indices,
// predicated LDS atomics.
__global__ __launch_bounds__(256) void part_scan(
        const int* __restrict__ sbins, const unsigned* __restrict__ cnt_s,
        const float* __restrict__ w, float* __restrict__ partials,
        int N, int nbkt) {
    const int s = blockIdx.x, q = blockIdx.y, g = blockIdx.z;
    const int* sq = sbins + ((size_t)(g * nbkt + q) * NBB + s * CPS) * SLOT;
    const unsigned* cq = cnt_s + (size_t)(g * nbkt + q) * NBB + s * CPS;
    const float* wg = w + (size_t)g * N;
    const int tid = threadIdx.x, wv = tid >> 6;
    __shared__ float bl[4][NPB];
    __shared__ unsigned lcnt[CPS];
    if (tid < CPS) lcnt[tid] = cq[tid];
    for (int i = tid; i < 4 * NPB; i += 256) ((float*)bl)[i] = 0.f;
    __syncthreads();
    float* mybl = bl[wv];
    const int4* s4 = (const int4*)sq;
    int4 v[4]; int limv[4];
    #pragma unroll
    for (int it = 0; it < 4; ++it) v[it] = s4[it * 256 + tid];      // unconditional
    #pragma unroll
    for (int it = 0; it < 4; ++it) {
        int i = it * 256 + tid;
        limv[it] = (int)lcnt[i >> 5] - ((i & 31) << 2);
    }
    float va[4][4];
    #pragma unroll
    for (int it = 0; it < 4; ++it) {   // branch-free, garbage idx clamped to 0
        int i0 = (limv[it] > 0) ? (v[it].x & 0x1FFFF) : 0;
        int i1 = (limv[it] > 1) ? (v[it].y & 0x1FFFF) : 0;
        int i2 = (limv[it] > 2) ? (v[it].z & 0x1FFFF) : 0;
        int i3 = (limv[it] > 3) ? (v[it].w & 0x1FFFF) : 0;
        va[it][0] = wg[i0];
        va[it][1] = wg[i1];
        va[it][2] = wg[i2];
        va[it][3] = wg[i3];
    }
    #pragma unroll
    for (int it = 0; it < 4; ++it) {
        if (limv[it] > 0) atomicAdd(&mybl[(((unsigned)v[it].x) >> 17) & 511], va[it][0]);
        if (limv[it] > 1) atomicAdd(&mybl[(((unsigned)v[it].y) >> 17) & 511], va[it][1]);
        if (limv[it] > 2) atomicAdd(&mybl[(((unsigned)v[it].z) >> 17) & 511], va[it][2]);
        if (limv[it] > 3) atomicAdd(&mybl[(((unsigned)v[it].w) >> 17) & 511], va[it][3]);
    }
    __syncthreads();
    float* pp = partials + (((size_t)(g * nbkt + q)) * SB + s) * NPB;
    for (int i = tid; i < NPB; i += 256)
        pp[i] = bl[0][i] + bl[1][i] + bl[2][i] + bl[3][i];
}

// prop combine, fine-grained: 128 thr, block covers 128 nodes.
__global__ __launch_bounds__(128) void prop_combine(
        const float* __restrict__ partials, const float* __restrict__ inv,
        float* __restrict__ out_w, float* __restrict__ sums, int s_idx,
        int N, int nbkt, float scale) {
    const int qb = blockIdx.x, g = blockIdx.y;
    const int q = qb >> 2, r = qb & 3;
    const int tid = threadIdx.x, wv = tid >> 6, lane = tid & 63;
    const float* pp = partials + ((size_t)(g * nbkt + q)) * SB * NPB + r * 128 + tid;
    float t = 0.f;
    #pragma unroll
    for (int s = 0; s < SB; ++s) t += pp[(size_t)s * NPB];
    const float u = t * scale;
    const int node = q * NPB + r * 128 + tid;
    const bool valid = node < N;
    if (valid) {
        size_t off = (size_t)g * N + node;
        out_w[off] = u * inv[off];
    }
    float red = valid ? u : 0.f;
    #pragma unroll
    for (int off2 = 32; off2 > 0; off2 >>= 1) red += __shfl_down(red, off2);
    __shared__ float wsum[2];
    if (lane == 0) wsum[wv] = red;
    __syncthreads();
    if (tid == 0) {
        float sm = wsum[0] + wsum[1];
        if (sm != 0.f) atomicAdd(&sums[g * 2 + s_idx], sm);
    }
}

// pass-3 combine + featsum, float4: block (r,q,g) handles 64 rows.
__global__ __launch_bounds__(512) void feat_combine(
        const float* __restrict__ partials,
        const float* __restrict__ feat_p, const float* __restrict__ feat_s,
        float* __restrict__ fpart2, int N, int nbkt) {
    const int r = blockIdx.x, q = blockIdx.y, g = blockIdx.z;
    const int tid = threadIdx.x;
    const int base = q * NPB + r * 64;
    __shared__ float tmp[SB][64];
    __shared__ float red[64];
    __shared__ float4 sm4[512];
    const float* pp = partials + ((size_t)(g * nbkt + q)) * SB * NPB + r * 64;
    {
        int s = tid >> 6, n = tid & 63;   // 8 slices x 64
        tmp[s][n] = pp[(size_t)s * NPB + n];
    }
    __syncthreads();
    if (tid < 64) {
        float t = 0.f;
        #pragma unroll
        for (int s = 0; s < SB; ++s) t += tmp[s][tid];
        red[tid] = (base + tid < N) ? t : 0.f;
    }
    __syncthreads();
    const float* feat = g ? feat_s : feat_p;
    const float4* f4 = (const float4*)feat;
    const int col4 = tid & 31, rg = tid >> 5;   // 16 row-groups x 4 rows
    float4 acc = make_float4(0.f, 0.f, 0.f, 0.f);
    #pragma unroll
    for (int k = 0; k < 4; ++k) {
        int row = rg * 4 + k;
        if (base + row < N) {
            float uu = red[row];
            float4 fv = f4[(size_t)(base + row) * 32 + col4];
            acc.x += uu * fv.x; acc.y += uu * fv.y;
            acc.z += uu * fv.z; acc.w += uu * fv.w;
        }
    }
    sm4[tid] = acc;
    __syncthreads();
    for (int st = 8; st > 0; st >>= 1) {
        if (rg < st) {
            float4 o = sm4[(rg + st) * 32 + col4];
            float4 a = sm4[rg * 32 + col4];
            a.x += o.x; a.y += o.y; a.z += o.z; a.w += o.w;
            sm4[rg * 32 + col4] = a;
        }
        __syncthreads();
    }
    if (tid < 32) {
        float4 t = sm4[tid];
        float* dstp = fpart2 + ((size_t)g * 32 + ((q * 8 + r) & 31)) * D + tid * 4;
        atomicAdd(dstp + 0, t.x);
        atomicAdd(dstp + 1, t.y);
        atomicAdd(dstp + 2, t.z);
        atomicAdd(dstp + 3, t.w);
    }
}

// 1024 threads: parallel per-graph chains using precomputed T0/Av/Bv.
__global__ __launch_bounds__(1024) void final_kernel(
        const float* __restrict__ fpart2, const float* __restrict__ sums,
        const float* __restrict__ W0, const float* __restrict__ T0,
        const float* __restrict__ Av, const float* __restrict__ Bv,
        const float* __restrict__ b2,
        const float* __restrict__ Wr, const float* __restrict__ br,
        const float* __restrict__ Wm1, const float* __restrict__ bm1,
        const float* __restrict__ Wm2, const float* __restrict__ bm2,
        float* __restrict__ out) {
    __shared__ float x[2][128];
    __shared__ float part[2][4][128];
    __shared__ float rvec[256];
    __shared__ float gv[256];
    __shared__ float m1[128];
    const int tid = threadIdx.x;
    const int j = tid & 127;
    const int h = (tid >> 7) & 3;
    const int gg = tid >> 9;

    auto mv128 = [&](const float* __restrict__ W, float* __restrict__ buf) {
        float p = 0.f;
        const float* Wp = W + (size_t)(h * 32) * 128 + j;
        #pragma unroll
        for (int i = 0; i < 32; ++i) p += buf[h * 32 + i] * Wp[(size_t)i * 128];
        part[gg][h][j] = p;
        __syncthreads();
        if (h == 0)
            buf[j] = part[gg][0][j] + part[gg][1][j] + part[gg][2][j] + part[gg][3][j];
        __syncthreads();
    };

    if (tid < 256) {
        int g = tid >> 7;
        const float* fp = fpart2 + (size_t)g * 4096 + (tid & 127);
        float rv = 0.f;
        #pragma unroll
        for (int b = 0; b < 32; ++b) rv += fp[(size_t)b * 128];
        rvec[tid] = rv;
    }
    __syncthreads();

    {
        const float s1 = sums[gg * 2 + 0];
        const float s2 = sums[gg * 2 + 1];
        if (h == 0) x[gg][j] = rvec[gg * 128 + j];
        __syncthreads();
        mv128(W0, x[gg]);
        mv128(T0, x[gg]);
        if (h == 0) x[gg][j] += s2 * Av[j] + s1 * Bv[j] + b2[j];
        __syncthreads();
        mv128(Wr, x[gg]);
        if (h == 0) gv[gg * 128 + j] = 1.0f / (1.0f + expf(-(x[gg][j] + br[j])));
        __syncthreads();
    }

    {
        float p = 0.f;
        const float* Wp = Wm1 + (size_t)(h * 64) * 128 + j;
        #pragma unroll
        for (int i = 0; i < 64; ++i) p += gv[h * 64 + i] * Wp[(size_t)i * 128];
        part[gg][h][j] = p;
        __syncthreads();
        if (tid < 128)
            m1[j] = (part[0][0][j] + part[0][1][j] + part[0][2][j] + part[0][3][j]
                     + bm1[j]) * Wm2[j];
        __syncthreads();
        if (tid < 64) m1[tid] += m1[tid + 64];
        __syncthreads();
        if (tid < 32) m1[tid] += m1[tid + 32];
        __syncthreads();
        if (tid < 16) m1[tid] += m1[tid + 16];
        __syncthreads();
        if (tid < 8) m1[tid] += m1[tid + 8];
        __syncthreads();
        if (tid < 4) m1[tid] += m1[tid + 4];
        __syncthreads();
        if (tid < 2) m1[tid] += m1[tid + 2];
        __syncthreads();
        if (tid == 0) out[0] = 1.0f / (1.0f + expf(-(m1[0] + m1[1] + bm2[0])));
    }
}

extern "C" void kernel_launch(void* const* d_in, const int* in_sizes, int n_in,
                              void* d_out, int out_size, void* d_ws, size_t ws_size,
                              hipStream_t stream) {
    const float* feat_p = (const float*)d_in[0];
    const int*   src_p  = (const int*)d_in[1];
    const int*   dst_p  = (const int*)d_in[2];
    const float* feat_s = (const float*)d_in[3];
    const int*   src_s  = (const int*)d_in[4];
    const int*   dst_s  = (const int*)d_in[5];
    const float* W0 = (const float*)d_in[6];
    const float* b0 = (const float*)d_in[7];
    const float* W1 = (const float*)d_in[8];
    const float* b1 = (const float*)d_in[9];
    const float* W2 = (const float*)d_in[10];
    const float* b2 = (const float*)d_in[11];
    const float* Wr = (const float*)d_in[12];
    const float* br = (const float*)d_in[13];
    const float* Wm1 = (const float*)d_in[14];
    const float* bm1 = (const float*)d_in[15];
    const float* Wm2 = (const float*)d_in[16];
    const float* bm2 = (const float*)d_in[17];
    float* out = (float*)d_out;

    const int N = in_sizes[0] / D;   // 50000
    const int E = in_sizes[1];       // 1600000
    const int N2 = 2 * N;
    const int nbkt = (N + NPB - 1) >> BSH;   // 98

    // ws (floats): sums[16] | fpart2[2*32*128] | T0[16384] | Av[128] | Bv[128] |
    //   inv[2N] | w1[2N] | w2[2N] | partials[2*nbkt*SB*NPB] |
    //   cnt_s[2*nbkt*NBB u32] | cnt_d | sbins[2*nbkt*NBB*SLOT int] | dbins[ushort]
    float* ws     = (float*)d_ws;
    float* sums   = ws;
    float* fpart2 = ws + 16;
    float* T0     = fpart2 + 2 * 32 * 128;
    float* Av     = T0 + 128 * 128;
    float* Bv     = Av + 128;
    float* inv    = Bv + 128;
    float* w1     = inv + N2;
    float* w2     = w1 + N2;
    float* partials = w2 + N2;
    unsigned* cnt_s = (unsigned*)(partials + (size_t)2 * nbkt * SB * NPB);
    unsigned* cnt_d = cnt_s + (size_t)2 * nbkt * NBB;
    int* sbins    = (int*)(cnt_d + (size_t)2 * nbkt * NBB);
    unsigned short* dbins = (unsigned short*)(sbins + (size_t)2 * nbkt * NBB * SLOT);

    const float u0 = 1.0f / (float)N;
    const int zcount = 16 + 2 * 32 * 128;    // sums + fpart2 (zeroed in deg_combine)

    bin_kernel<<<dim3(NBB + 1, 2, 2), 512, 0, stream>>>(
        src_p, dst_p, src_s, dst_s, sbins, dbins, cnt_s, cnt_d,
        W1, W2, b0, b1, T0, Av, Bv, E, nbkt);

    deg_part<<<dim3(SB, nbkt, 2), 256, 0, stream>>>(dbins, cnt_d, partials, nbkt);
    deg_combine<<<dim3(nbkt, 2), 512, 0, stream>>>(partials, inv, ws, zcount,
                                                   N, nbkt);

    part_scan<<<dim3(SB, nbkt, 2), 256, 0, stream>>>(sbins, cnt_s, inv,
                                                     partials, N, nbkt);
    prop_combine<<<dim3(nbkt * 4, 2), 128, 0, stream>>>(partials, inv, w1,
                                                        sums, 0, N, nbkt, u0);

    part_scan<<<dim3(SB, nbkt, 2), 256, 0, stream>>>(sbins, cnt_s, w1,
                                                     partials, N, nbkt);
    prop_combine<<<dim3(nbkt * 4, 2), 128, 0, stream>>>(partials, inv, w2,
                                                        sums, 1, N, nbkt, 1.0f);

    part_scan<<<dim3(SB, nbkt, 2), 256, 0, stream>>>(sbins, cnt_s, w2,
                                                     partials, N, nbkt);
    feat_combine<<<dim3(8, nbkt, 2), 512, 0, stream>>>(partials, feat_p, feat_s,
                                                       fpart2, N, nbkt);

    final_kernel<<<1, 1024, 0, stream>>>(fpart2, sums, W0, T0, Av, Bv, b2,
                                         Wr, br, Wm1, bm1, Wm2, bm2, out);
}

// Round 12
// 276.763 us; speedup vs baseline: 1.1485x; 1.1485x over previous
//
#include <hip/hip_runtime.h>
#include <math.h>

#define D 128
#define BSH 9        // bucket shift: 512 nodes/bucket
#define NPB 512      // nodes per bucket
#define SLOT 128     // slots per (bucket, bin-block): mean 64, 8-sigma headroom
#define STCAP 6252   // edges per bin block (mult of 4)
#define NBB 256      // bin blocks per graph
#define NBKT_MAX 128
#define SB 8         // sub-blocks per bucket in part passes
#define CPS (NBB / SB)   // bin-chunks per sub-block = 32

// ---------------------------------------------------------------------------
// Collapsed linear GCN (math unchanged):
//   u0 = 1/N,  u_{k+1}[s] = sum_{e: src_e=s} inv_deg[dst_e] * u_k[dst_e]
//   mean(h3) = r@W0W1W2 + s2*(b0@W1W2) + s1*(b1@W2) + b2,  r = u3^T feat
// MEASURED LESSONS:
//   R9-R11: kernel boundaries are the only cheap cross-XCD coherence.
//   R13: NEVER scatter-atomic at E scale; atomics on FEW addresses fine.
//   R14: ballot-ranking binning = VALU-bound. R15: 4B scatter = 7x write amp.
//   R16: per-kernel cost ~3x traffic roofline. R17: grid >= CUs always.
//   R18-R20: ILP/branch-free passes worth ~10us each.
//   R21: dense cursor bins REGRESSED +15us (unaligned run boundaries).
//   R22: gather-clamp + replicated histogram = null; plateau ~276.
//   R23: wprep-in-bin + 128thr combine REGRESSED +40us (serial wprep block
//        stretches bin tail). Counters: bin = 1.55M LDS conflicts, 10% BW,
//        8% VALU -> staging-cursor same-address serialization is bin's cost.
// R24 (this round): R22 revert + ONE change: 4-replica staging cursors in
//   bin phase 2 (rcur4[rep][q] seeded offs[q]+prefix(hist4)) -> 4x less
//   same-address LDS atomic contention. Formats/downstream unchanged.
// ---------------------------------------------------------------------------

// Counting-sort binning, deterministic slots, one side per block.
//   side 0 (src): payload (src&511)<<17 | dst   (dst < 2^17)
//   side 1 (dst): payload ushort (dst&511)
__global__ __launch_bounds__(512) void bin_kernel(
        const int* __restrict__ src_p, const int* __restrict__ dst_p,
        const int* __restrict__ src_s, const int* __restrict__ dst_s,
        int* __restrict__ sbins, unsigned short* __restrict__ dbins,
        unsigned* __restrict__ cnt_s, unsigned* __restrict__ cnt_d,
        int E, int nbkt) {
    const int b = blockIdx.x, side = blockIdx.y, g = blockIdx.z;
    const int* src = g ? src_s : src_p;
    const int* dst = g ? dst_s : dst_p;
    const int* key = side ? dst : src;

    __shared__ int stage[STCAP];            // side1 aliases as ushort
    __shared__ unsigned hist4[4][NBKT_MAX];
    __shared__ unsigned rcur4[4][NBKT_MAX];
    __shared__ unsigned hist[NBKT_MAX], offs[NBKT_MAX];

    const int tid = threadIdx.x;
    const int wv = tid >> 6, lane = tid & 63;
    const int rep = tid >> 7;               // 4 replicas (128 threads each)
    for (int i = tid; i < 4 * NBKT_MAX; i += 512) ((unsigned*)hist4)[i] = 0u;
    __syncthreads();

    const int e0 = b * STCAP;
    const int e1 = min(e0 + STCAP, E);
    const int efull = e0 + ((e1 - e0) & ~3);

    // phase 1: replicated histogram of keys
    for (int e = e0 + tid * 4; e + 4 <= e1; e += 512 * 4) {
        int4 k4 = *(const int4*)(key + e);
        atomicAdd(&hist4[rep][k4.x >> BSH], 1u);
        atomicAdd(&hist4[rep][k4.y >> BSH], 1u);
        atomicAdd(&hist4[rep][k4.z >> BSH], 1u);
        atomicAdd(&hist4[rep][k4.w >> BSH], 1u);
    }
    for (int e = efull + tid; e < e1; e += 512)
        atomicAdd(&hist4[rep][key[e] >> BSH], 1u);
    __syncthreads();
    if (tid < NBKT_MAX)
        hist[tid] = hist4[0][tid] + hist4[1][tid] + hist4[2][tid] + hist4[3][tid];
    __syncthreads();

    // wave 0: exclusive scan of totals
    if (wv == 0) {
        unsigned a = (2 * lane < nbkt) ? hist[2 * lane] : 0u;
        unsigned bb = (2 * lane + 1 < nbkt) ? hist[2 * lane + 1] : 0u;
        unsigned v = a + bb;
        for (int d2 = 1; d2 < 64; d2 <<= 1) {
            unsigned t = __shfl_up(v, d2);
            if (lane >= d2) v += t;
        }
        unsigned ex = v - (a + bb);
        if (2 * lane < nbkt) offs[2 * lane] = ex;
        if (2 * lane + 1 < nbkt) offs[2 * lane + 1] = ex + a;
    }
    __syncthreads();
    // per-replica cursor seed: offs[q] + prefix of hist4 over replicas
    if (tid < NBKT_MAX) {
        unsigned o = offs[tid];
        rcur4[0][tid] = o; o += hist4[0][tid];
        rcur4[1][tid] = o; o += hist4[1][tid];
        rcur4[2][tid] = o; o += hist4[2][tid];
        rcur4[3][tid] = o;
    }
    __syncthreads();

    if (side == 0) {
        for (int e = e0 + tid * 4; e + 4 <= e1; e += 512 * 4) {
            int4 s4 = *(const int4*)(src + e);
            int4 d4 = *(const int4*)(dst + e);
            int sv[4] = {s4.x, s4.y, s4.z, s4.w};
            int dv[4] = {d4.x, d4.y, d4.z, d4.w};
            #pragma unroll
            for (int k = 0; k < 4; ++k) {
                unsigned p = atomicAdd(&rcur4[rep][sv[k] >> BSH], 1u);
                stage[p] = ((sv[k] & (NPB - 1)) << 17) | dv[k];
            }
        }
        for (int e = efull + tid; e < e1; e += 512) {
            int s = src[e], d2 = dst[e];
            unsigned p = atomicAdd(&rcur4[rep][s >> BSH], 1u);
            stage[p] = ((s & (NPB - 1)) << 17) | d2;
        }
        __syncthreads();
        int* sb = sbins + (size_t)g * nbkt * NBB * SLOT;
        unsigned* csp = cnt_s + (size_t)g * nbkt * NBB;
        for (int q = wv; q < nbkt; q += 8) {
            unsigned cs = min(hist[q], (unsigned)SLOT);
            unsigned os = offs[q];
            int* dp = sb + ((size_t)q * NBB + b) * SLOT;
            for (unsigned i = lane; i < cs; i += 64) dp[i] = stage[os + i];
            if (lane == 0) csp[q * NBB + b] = cs;
        }
    } else {
        unsigned short* st = (unsigned short*)stage;
        for (int e = e0 + tid * 4; e + 4 <= e1; e += 512 * 4) {
            int4 d4 = *(const int4*)(dst + e);
            int dv[4] = {d4.x, d4.y, d4.z, d4.w};
            #pragma unroll
            for (int k = 0; k < 4; ++k) {
                unsigned p = atomicAdd(&rcur4[rep][dv[k] >> BSH], 1u);
                st[p] = (unsigned short)(dv[k] & (NPB - 1));
            }
        }
        for (int e = efull + tid; e < e1; e += 512) {
            int d2 = dst[e];
            unsigned p = atomicAdd(&rcur4[rep][d2 >> BSH], 1u);
            st[p] = (unsigned short)(d2 & (NPB - 1));
        }
        __syncthreads();
        unsigned short* db = dbins + (size_t)g * nbkt * NBB * SLOT;
        unsigned* cdp = cnt_d + (size_t)g * nbkt * NBB;
        for (int q = wv; q < nbkt; q += 8) {
            unsigned cd = min(hist[q], (unsigned)SLOT);
            unsigned od = offs[q];
            unsigned short* ddp = db + ((size_t)q * NBB + b) * SLOT;
            for (unsigned i = lane; i < cd; i += 64) ddp[i] = st[od + i];
            if (lane == 0) cdp[q * NBB + b] = cd;
        }
    }
}

// deg partial: 256 thr, 4 replicas, unconditional loads, predicated atomics.
__global__ __launch_bounds__(256) void deg_part(
        const unsigned short* __restrict__ dbins, const unsigned* __restrict__ cnt_d,
        float* __restrict__ partials, int nbkt) {
    const int s = blockIdx.x, q = blockIdx.y, g = blockIdx.z;
    const unsigned short* dq = dbins + ((size_t)(g * nbkt + q) * NBB + s * CPS) * SLOT;
    const unsigned* cq = cnt_d + (size_t)(g * nbkt + q) * NBB + s * CPS;
    const int tid = threadIdx.x, wv = tid >> 6;
    __shared__ float bl[4][NPB];
    __shared__ unsigned lcnt[CPS];
    if (tid < CPS) lcnt[tid] = cq[tid];
    for (int i = tid; i < 4 * NPB; i += 256) ((float*)bl)[i] = 0.f;
    __syncthreads();
    float* mybl = bl[wv];
    const ushort4* d4 = (const ushort4*)dq;
    ushort4 v[4]; int limv[4];
    #pragma unroll
    for (int it = 0; it < 4; ++it) v[it] = d4[it * 256 + tid];      // unconditional
    #pragma unroll
    for (int it = 0; it < 4; ++it) {
        int i = it * 256 + tid;
        limv[it] = (int)lcnt[i >> 5] - ((i & 31) << 2);
    }
    #pragma unroll
    for (int it = 0; it < 4; ++it) {
        if (limv[it] > 0) atomicAdd(&mybl[v[it].x & 511], 1.f);
        if (limv[it] > 1) atomicAdd(&mybl[v[it].y & 511], 1.f);
        if (limv[it] > 2) atomicAdd(&mybl[v[it].z & 511], 1.f);
        if (limv[it] > 3) atomicAdd(&mybl[v[it].w & 511], 1.f);
    }
    __syncthreads();
    float* pp = partials + (((size_t)(g * nbkt + q)) * SB + s) * NPB;
    for (int i = tid; i < NPB; i += 256)
        pp[i] = bl[0][i] + bl[1][i] + bl[2][i] + bl[3][i];
}

// deg combine: inv = 1/max(deg,1); block (0,0) zeroes sums+fpart2.
__global__ __launch_bounds__(512) void deg_combine(
        const float* __restrict__ partials, float* __restrict__ inv,
        float* __restrict__ zbase, int zcount, int N, int nbkt) {
    const int q = blockIdx.x, g = blockIdx.y;
    const int tid = threadIdx.x;
    if (q == 0 && g == 0)
        for (int i = tid; i < zcount; i += 512) zbase[i] = 0.f;
    const float* pp = partials + ((size_t)(g * nbkt + q)) * SB * NPB;
    float t = 0.f;
    #pragma unroll
    for (int s = 0; s < SB; ++s) t += pp[s * NPB + tid];
    const int node = q * NPB + tid;
    if (node < N) inv[(size_t)g * N + node] = 1.0f / fmaxf(t, 1.0f);
}

// prop partial: unconditional slot loads, clamped gather indices,
// predicated LDS atomics.
__global__ __launch_bounds__(256) void part_scan(
        const int* __restrict__ sbins, const unsigned* __restrict__ cnt_s,
        const float* __restrict__ w, float* __restrict__ partials,
        int N, int nbkt) {
    const int s = blockIdx.x, q = blockIdx.y, g = blockIdx.z;
    const int* sq = sbins + ((size_t)(g * nbkt + q) * NBB + s * CPS) * SLOT;
    const unsigned* cq = cnt_s + (size_t)(g * nbkt + q) * NBB + s * CPS;
    const float* wg = w + (size_t)g * N;
    const int tid = threadIdx.x, wv = tid >> 6;
    __shared__ float bl[4][NPB];
    __shared__ unsigned lcnt[CPS];
    if (tid < CPS) lcnt[tid] = cq[tid];
    for (int i = tid; i < 4 * NPB; i += 256) ((float*)bl)[i] = 0.f;
    __syncthreads();
    float* mybl = bl[wv];
    const int4* s4 = (const int4*)sq;
    int4 v[4]; int limv[4];
    #pragma unroll
    for (int it = 0; it < 4; ++it) v[it] = s4[it * 256 + tid];      // unconditional
    #pragma unroll
    for (int it = 0; it < 4; ++it) {
        int i = it * 256 + tid;
        limv[it] = (int)lcnt[i >> 5] - ((i & 31) << 2);
    }
    float va[4][4];
    #pragma unroll
    for (int it = 0; it < 4; ++it) {   // branch-free, garbage idx clamped to 0
        int i0 = (limv[it] > 0) ? (v[it].x & 0x1FFFF) : 0;
        int i1 = (limv[it] > 1) ? (v[it].y & 0x1FFFF) : 0;
        int i2 = (limv[it] > 2) ? (v[it].z & 0x1FFFF) : 0;
        int i3 = (limv[it] > 3) ? (v[it].w & 0x1FFFF) : 0;
        va[it][0] = wg[i0];
        va[it][1] = wg[i1];
        va[it][2] = wg[i2];
        va[it][3] = wg[i3];
    }
    #pragma unroll
    for (int it = 0; it < 4; ++it) {
        if (limv[it] > 0) atomicAdd(&mybl[(((unsigned)v[it].x) >> 17) & 511], va[it][0]);
        if (limv[it] > 1) atomicAdd(&mybl[(((unsigned)v[it].y) >> 17) & 511], va[it][1]);
        if (limv[it] > 2) atomicAdd(&mybl[(((unsigned)v[it].z) >> 17) & 511], va[it][2]);
        if (limv[it] > 3) atomicAdd(&mybl[(((unsigned)v[it].w) >> 17) & 511], va[it][3]);
    }
    __syncthreads();
    float* pp = partials + (((size_t)(g * nbkt + q)) * SB + s) * NPB;
    for (int i = tid; i < NPB; i += 256)
        pp[i] = bl[0][i] + bl[1][i] + bl[2][i] + bl[3][i];
}

// prop combine: u = scale * sum_s partials; out_w = u*inv; Σu via shfl.
__global__ __launch_bounds__(512) void prop_combine(
        const float* __restrict__ partials, const float* __restrict__ inv,
        float* __restrict__ out_w, float* __restrict__ sums, int s_idx,
        int N, int nbkt, float scale) {
    const int q = blockIdx.x, g = blockIdx.y;
    const int tid = threadIdx.x, wv = tid >> 6, lane = tid & 63;
    const float* pp = partials + ((size_t)(g * nbkt + q)) * SB * NPB;
    float t = 0.f;
    #pragma unroll
    for (int s = 0; s < SB; ++s) t += pp[s * NPB + tid];
    const float u = t * scale;
    const int node = q * NPB + tid;
    const bool valid = node < N;
    if (valid) {
        size_t off = (size_t)g * N + node;
        out_w[off] = u * inv[off];
    }
    float r = valid ? u : 0.f;
    #pragma unroll
    for (int off = 32; off > 0; off >>= 1) r += __shfl_down(r, off);
    __shared__ float wsum[8];
    if (lane == 0) wsum[wv] = r;
    __syncthreads();
    if (tid == 0) {
        float s = wsum[0] + wsum[1] + wsum[2] + wsum[3]
                + wsum[4] + wsum[5] + wsum[6] + wsum[7];
        if (s != 0.f) atomicAdd(&sums[g * 2 + s_idx], s);
    }
}

// pass-3 combine + featsum, float4: block (r,q,g) handles 64 rows.
__global__ __launch_bounds__(512) void feat_combine(
        const float* __restrict__ partials,
        const float* __restrict__ feat_p, const float* __restrict__ feat_s,
        float* __restrict__ fpart2, int N, int nbkt) {
    const int r = blockIdx.x, q = blockIdx.y, g = blockIdx.z;
    const int tid = threadIdx.x;
    const int base = q * NPB + r * 64;
    __shared__ float tmp[SB][64];
    __shared__ float red[64];
    __shared__ float4 sm4[512];
    const float* pp = partials + ((size_t)(g * nbkt + q)) * SB * NPB + r * 64;
    {
        int s = tid >> 6, n = tid & 63;   // 8 slices x 64
        tmp[s][n] = pp[(size_t)s * NPB + n];
    }
    __syncthreads();
    if (tid < 64) {
        float t = 0.f;
        #pragma unroll
        for (int s = 0; s < SB; ++s) t += tmp[s][tid];
        red[tid] = (base + tid < N) ? t : 0.f;
    }
    __syncthreads();
    const float* feat = g ? feat_s : feat_p;
    const float4* f4 = (const float4*)feat;
    const int col4 = tid & 31, rg = tid >> 5;   // 16 row-groups x 4 rows
    float4 acc = make_float4(0.f, 0.f, 0.f, 0.f);
    #pragma unroll
    for (int k = 0; k < 4; ++k) {
        int row = rg * 4 + k;
        if (base + row < N) {
            float uu = red[row];
            float4 fv = f4[(size_t)(base + row) * 32 + col4];
            acc.x += uu * fv.x; acc.y += uu * fv.y;
            acc.z += uu * fv.z; acc.w += uu * fv.w;
        }
    }
    sm4[tid] = acc;
    __syncthreads();
    for (int st = 8; st > 0; st >>= 1) {
        if (rg < st) {
            float4 o = sm4[(rg + st) * 32 + col4];
            float4 a = sm4[rg * 32 + col4];
            a.x += o.x; a.y += o.y; a.z += o.z; a.w += o.w;
            sm4[rg * 32 + col4] = a;
        }
        __syncthreads();
    }
    if (tid < 32) {
        float4 t = sm4[tid];
        float* dstp = fpart2 + ((size_t)g * 32 + ((q * 8 + r) & 31)) * D + tid * 4;
        atomicAdd(dstp + 0, t.x);
        atomicAdd(dstp + 1, t.y);
        atomicAdd(dstp + 2, t.z);
        atomicAdd(dstp + 3, t.w);
    }
}

// weight pre-collapse: T0 = W1@W2 (blocks 0..63), Av = (b0@W1)@W2 (block 64),
// Bv = b1@W2 (block 65).
__global__ __launch_bounds__(256) void wprep(
        const float* __restrict__ W1, const float* __restrict__ W2,
        const float* __restrict__ b0, const float* __restrict__ b1,
        float* __restrict__ T0, float* __restrict__ Av, float* __restrict__ Bv) {
    const int b = blockIdx.x, tid = threadIdx.x;
    if (b < 64) {
        const int row = 2 * b + (tid >> 7), col = tid & 127;
        float acc = 0.f;
        const float* w1r = W1 + (size_t)row * 128;
        #pragma unroll 8
        for (int k = 0; k < 128; ++k) acc += w1r[k] * W2[(size_t)k * 128 + col];
        T0[(size_t)row * 128 + col] = acc;
    } else if (b == 64) {
        __shared__ float bv[128];
        if (tid < 128) {
            float a = 0.f;
            #pragma unroll 8
            for (int i = 0; i < 128; ++i) a += b0[i] * W1[(size_t)i * 128 + tid];
            bv[tid] = a;
        }
        __syncthreads();
        if (tid < 128) {
            float a = 0.f;
            #pragma unroll 8
            for (int i = 0; i < 128; ++i) a += bv[i] * W2[(size_t)i * 128 + tid];
            Av[tid] = a;
        }
    } else {
        if (tid < 128) {
            float a = 0.f;
            #pragma unroll 8
            for (int i = 0; i < 128; ++i) a += b1[i] * W2[(size_t)i * 128 + tid];
            Bv[tid] = a;
        }
    }
}

// 1024 threads: parallel per-graph chains using precomputed T0/Av/Bv.
__global__ __launch_bounds__(1024) void final_kernel(
        const float* __restrict__ fpart2, const float* __restrict__ sums,
        const float* __restrict__ W0, const float* __restrict__ T0,
        const float* __restrict__ Av, const float* __restrict__ Bv,
        const float* __restrict__ b2,
        const float* __restrict__ Wr, const float* __restrict__ br,
        const float* __restrict__ Wm1, const float* __restrict__ bm1,
        const float* __restrict__ Wm2, const float* __restrict__ bm2,
        float* __restrict__ out) {
    __shared__ float x[2][128];
    __shared__ float part[2][4][128];
    __shared__ float rvec[256];
    __shared__ float gv[256];
    __shared__ float m1[128];
    const int tid = threadIdx.x;
    const int j = tid & 127;
    const int h = (tid >> 7) & 3;
    const int gg = tid >> 9;

    auto mv128 = [&](const float* __restrict__ W, float* __restrict__ buf) {
        float p = 0.f;
        const float* Wp = W + (size_t)(h * 32) * 128 + j;
        #pragma unroll
        for (int i = 0; i < 32; ++i) p += buf[h * 32 + i] * Wp[(size_t)i * 128];
        part[gg][h][j] = p;
        __syncthreads();
        if (h == 0)
            buf[j] = part[gg][0][j] + part[gg][1][j] + part[gg][2][j] + part[gg][3][j];
        __syncthreads();
    };

    if (tid < 256) {
        int g = tid >> 7;
        const float* fp = fpart2 + (size_t)g * 4096 + (tid & 127);
        float rv = 0.f;
        #pragma unroll
        for (int b = 0; b < 32; ++b) rv += fp[(size_t)b * 128];
        rvec[tid] = rv;
    }
    __syncthreads();

    {
        const float s1 = sums[gg * 2 + 0];
        const float s2 = sums[gg * 2 + 1];
        if (h == 0) x[gg][j] = rvec[gg * 128 + j];
        __syncthreads();
        mv128(W0, x[gg]);
        mv128(T0, x[gg]);
        if (h == 0) x[gg][j] += s2 * Av[j] + s1 * Bv[j] + b2[j];
        __syncthreads();
        mv128(Wr, x[gg]);
        if (h == 0) gv[gg * 128 + j] = 1.0f / (1.0f + expf(-(x[gg][j] + br[j])));
        __syncthreads();
    }

    {
        float p = 0.f;
        const float* Wp = Wm1 + (size_t)(h * 64) * 128 + j;
        #pragma unroll
        for (int i = 0; i < 64; ++i) p += gv[h * 64 + i] * Wp[(size_t)i * 128];
        part[gg][h][j] = p;
        __syncthreads();
        if (tid < 128)
            m1[j] = (part[0][0][j] + part[0][1][j] + part[0][2][j] + part[0][3][j]
                     + bm1[j]) * Wm2[j];
        __syncthreads();
        if (tid < 64) m1[tid] += m1[tid + 64];
        __syncthreads();
        if (tid < 32) m1[tid] += m1[tid + 32];
        __syncthreads();
        if (tid < 16) m1[tid] += m1[tid + 16];
        __syncthreads();
        if (tid < 8) m1[tid] += m1[tid + 8];
        __syncthreads();
        if (tid < 4) m1[tid] += m1[tid + 4];
        __syncthreads();
        if (tid < 2) m1[tid] += m1[tid + 2];
        __syncthreads();
        if (tid == 0) out[0] = 1.0f / (1.0f + expf(-(m1[0] + m1[1] + bm2[0])));
    }
}

extern "C" void kernel_launch(void* const* d_in, const int* in_sizes, int n_in,
                              void* d_out, int out_size, void* d_ws, size_t ws_size,
                              hipStream_t stream) {
    const float* feat_p = (const float*)d_in[0];
    const int*   src_p  = (const int*)d_in[1];
    const int*   dst_p  = (const int*)d_in[2];
    const float* feat_s = (const float*)d_in[3];
    const int*   src_s  = (const int*)d_in[4];
    const int*   dst_s  = (const int*)d_in[5];
    const float* W0 = (const float*)d_in[6];
    const float* b0 = (const float*)d_in[7];
    const float* W1 = (const float*)d_in[8];
    const float* b1 = (const float*)d_in[9];
    const float* W2 = (const float*)d_in[10];
    const float* b2 = (const float*)d_in[11];
    const float* Wr = (const float*)d_in[12];
    const float* br = (const float*)d_in[13];
    const float* Wm1 = (const float*)d_in[14];
    const float* bm1 = (const float*)d_in[15];
    const float* Wm2 = (const float*)d_in[16];
    const float* bm2 = (const float*)d_in[17];
    float* out = (float*)d_out;

    const int N = in_sizes[0] / D;   // 50000
    const int E = in_sizes[1];       // 1600000
    const int N2 = 2 * N;
    const int nbkt = (N + NPB - 1) >> BSH;   // 98

    // ws (floats): sums[16] | fpart2[2*32*128] | T0[16384] | Av[128] | Bv[128] |
    //   inv[2N] | w1[2N] | w2[2N] | partials[2*nbkt*SB*NPB] |
    //   cnt_s[2*nbkt*NBB u32] | cnt_d | sbins[2*nbkt*NBB*SLOT int] | dbins[ushort]
    float* ws     = (float*)d_ws;
    float* sums   = ws;
    float* fpart2 = ws + 16;
    float* T0     = fpart2 + 2 * 32 * 128;
    float* Av     = T0 + 128 * 128;
    float* Bv     = Av + 128;
    float* inv    = Bv + 128;
    float* w1     = inv + N2;
    float* w2     = w1 + N2;
    float* partials = w2 + N2;
    unsigned* cnt_s = (unsigned*)(partials + (size_t)2 * nbkt * SB * NPB);
    unsigned* cnt_d = cnt_s + (size_t)2 * nbkt * NBB;
    int* sbins    = (int*)(cnt_d + (size_t)2 * nbkt * NBB);
    unsigned short* dbins = (unsigned short*)(sbins + (size_t)2 * nbkt * NBB * SLOT);

    const float u0 = 1.0f / (float)N;
    const int zcount = 16 + 2 * 32 * 128;    // sums + fpart2 (zeroed in deg_combine)

    wprep<<<66, 256, 0, stream>>>(W1, W2, b0, b1, T0, Av, Bv);

    bin_kernel<<<dim3(NBB, 2, 2), 512, 0, stream>>>(src_p, dst_p, src_s, dst_s,
                                                    sbins, dbins, cnt_s, cnt_d,
                                                    E, nbkt);

    deg_part<<<dim3(SB, nbkt, 2), 256, 0, stream>>>(dbins, cnt_d, partials, nbkt);
    deg_combine<<<dim3(nbkt, 2), 512, 0, stream>>>(partials, inv, ws, zcount,
                                                   N, nbkt);

    part_scan<<<dim3(SB, nbkt, 2), 256, 0, stream>>>(sbins, cnt_s, inv,
                                                     partials, N, nbkt);
    prop_combine<<<dim3(nbkt, 2), 512, 0, stream>>>(partials, inv, w1,
                                                    sums, 0, N, nbkt, u0);

    part_scan<<<dim3(SB, nbkt, 2), 256, 0, stream>>>(sbins, cnt_s, w1,
                                                     partials, N, nbkt);
    prop_combine<<<dim3(nbkt, 2), 512, 0, stream>>>(partials, inv, w2,
                                                    sums, 1, N, nbkt, 1.0f);

    part_scan<<<dim3(SB, nbkt, 2), 256, 0, stream>>>(sbins, cnt_s, w2,
                                                     partials, N, nbkt);
    feat_combine<<<dim3(8, nbkt, 2), 512, 0, stream>>>(partials, feat_p, feat_s,
                                                       fpart2, N, nbkt);

    final_kernel<<<1, 1024, 0, stream>>>(fpart2, sums, W0, T0, Av, Bv, b2,
                                         Wr, br, Wm1, bm1, Wm2, bm2, out);
}

// Round 13
// 275.312 us; speedup vs baseline: 1.1546x; 1.0053x over previous
//
#include <hip/hip_runtime.h>
#include <math.h>

#define D 128
#define BSH 9        // bucket shift: 512 nodes/bucket
#define NPB 512      // nodes per bucket
#define SLOT 128     // slots per (bucket, bin-block): mean 64, 8-sigma headroom
#define STCAP 6252   // edges per bin block (mult of 4)
#define NBB 256      // bin blocks per graph
#define NBKT_MAX 128
#define SB 16        // sub-blocks per bucket in part passes (32 waves/CU)
#define CPS (NBB / SB)            // bin-chunks per sub-block = 16
#define ITN ((CPS * (SLOT / 4)) / 256)   // vec4 loads per thread = 2

// ---------------------------------------------------------------------------
// Collapsed linear GCN (math unchanged):
//   u0 = 1/N,  u_{k+1}[s] = sum_{e: src_e=s} inv_deg[dst_e] * u_k[dst_e]
//   mean(h3) = r@W0W1W2 + s2*(b0@W1W2) + s1*(b1@W2) + b2,  r = u3^T feat
// MEASURED LESSONS:
//   R9-R11: kernel boundaries are the only cheap cross-XCD coherence.
//   R13: NEVER scatter-atomic at E scale; atomics on FEW addresses fine.
//   R14: ballot-ranking binning = VALU-bound. R15: 4B scatter = 7x write amp.
//   R16: per-kernel cost ~3x traffic roofline. R17: grid >= CUs always.
//   R18-R20: ILP/branch-free passes worth ~10us each.
//   R21: dense cursor bins REGRESSED (unaligned run boundaries).
//   R22/R24: gather-clamp, replicated hist/cursors = null; plateau ~276.
//   R23: wprep-in-bin REGRESSED (serial block stretches bin tail).
//   No kernel BW- or compute-bound -> latency floor, not roofline.
// R25 (this round): max TLP for the latency-bound gather kernels:
//   SB 8->16 (grid 3136 x 256thr = 8 blocks/CU = 32 waves/CU, was 12).
//   Per-thread work halves; partials 16/bucket (6.4 MB, trivial).
// ---------------------------------------------------------------------------

// Counting-sort binning, deterministic slots, one side per block.
//   side 0 (src): payload (src&511)<<17 | dst   (dst < 2^17)
//   side 1 (dst): payload ushort (dst&511)
__global__ __launch_bounds__(512) void bin_kernel(
        const int* __restrict__ src_p, const int* __restrict__ dst_p,
        const int* __restrict__ src_s, const int* __restrict__ dst_s,
        int* __restrict__ sbins, unsigned short* __restrict__ dbins,
        unsigned* __restrict__ cnt_s, unsigned* __restrict__ cnt_d,
        int E, int nbkt) {
    const int b = blockIdx.x, side = blockIdx.y, g = blockIdx.z;
    const int* src = g ? src_s : src_p;
    const int* dst = g ? dst_s : dst_p;
    const int* key = side ? dst : src;

    __shared__ int stage[STCAP];            // side1 aliases as ushort
    __shared__ unsigned hist4[4][NBKT_MAX];
    __shared__ unsigned rcur4[4][NBKT_MAX];
    __shared__ unsigned hist[NBKT_MAX], offs[NBKT_MAX];

    const int tid = threadIdx.x;
    const int wv = tid >> 6, lane = tid & 63;
    const int rep = tid >> 7;               // 4 replicas (128 threads each)
    for (int i = tid; i < 4 * NBKT_MAX; i += 512) ((unsigned*)hist4)[i] = 0u;
    __syncthreads();

    const int e0 = b * STCAP;
    const int e1 = min(e0 + STCAP, E);
    const int efull = e0 + ((e1 - e0) & ~3);

    // phase 1: replicated histogram of keys
    for (int e = e0 + tid * 4; e + 4 <= e1; e += 512 * 4) {
        int4 k4 = *(const int4*)(key + e);
        atomicAdd(&hist4[rep][k4.x >> BSH], 1u);
        atomicAdd(&hist4[rep][k4.y >> BSH], 1u);
        atomicAdd(&hist4[rep][k4.z >> BSH], 1u);
        atomicAdd(&hist4[rep][k4.w >> BSH], 1u);
    }
    for (int e = efull + tid; e < e1; e += 512)
        atomicAdd(&hist4[rep][key[e] >> BSH], 1u);
    __syncthreads();
    if (tid < NBKT_MAX)
        hist[tid] = hist4[0][tid] + hist4[1][tid] + hist4[2][tid] + hist4[3][tid];
    __syncthreads();

    // wave 0: exclusive scan of totals
    if (wv == 0) {
        unsigned a = (2 * lane < nbkt) ? hist[2 * lane] : 0u;
        unsigned bb = (2 * lane + 1 < nbkt) ? hist[2 * lane + 1] : 0u;
        unsigned v = a + bb;
        for (int d2 = 1; d2 < 64; d2 <<= 1) {
            unsigned t = __shfl_up(v, d2);
            if (lane >= d2) v += t;
        }
        unsigned ex = v - (a + bb);
        if (2 * lane < nbkt) offs[2 * lane] = ex;
        if (2 * lane + 1 < nbkt) offs[2 * lane + 1] = ex + a;
    }
    __syncthreads();
    // per-replica cursor seed: offs[q] + prefix of hist4 over replicas
    if (tid < NBKT_MAX) {
        unsigned o = offs[tid];
        rcur4[0][tid] = o; o += hist4[0][tid];
        rcur4[1][tid] = o; o += hist4[1][tid];
        rcur4[2][tid] = o; o += hist4[2][tid];
        rcur4[3][tid] = o;
    }
    __syncthreads();

    if (side == 0) {
        for (int e = e0 + tid * 4; e + 4 <= e1; e += 512 * 4) {
            int4 s4 = *(const int4*)(src + e);
            int4 d4 = *(const int4*)(dst + e);
            int sv[4] = {s4.x, s4.y, s4.z, s4.w};
            int dv[4] = {d4.x, d4.y, d4.z, d4.w};
            #pragma unroll
            for (int k = 0; k < 4; ++k) {
                unsigned p = atomicAdd(&rcur4[rep][sv[k] >> BSH], 1u);
                stage[p] = ((sv[k] & (NPB - 1)) << 17) | dv[k];
            }
        }
        for (int e = efull + tid; e < e1; e += 512) {
            int s = src[e], d2 = dst[e];
            unsigned p = atomicAdd(&rcur4[rep][s >> BSH], 1u);
            stage[p] = ((s & (NPB - 1)) << 17) | d2;
        }
        __syncthreads();
        int* sb = sbins + (size_t)g * nbkt * NBB * SLOT;
        unsigned* csp = cnt_s + (size_t)g * nbkt * NBB;
        for (int q = wv; q < nbkt; q += 8) {
            unsigned cs = min(hist[q], (unsigned)SLOT);
            unsigned os = offs[q];
            int* dp = sb + ((size_t)q * NBB + b) * SLOT;
            for (unsigned i = lane; i < cs; i += 64) dp[i] = stage[os + i];
            if (lane == 0) csp[q * NBB + b] = cs;
        }
    } else {
        unsigned short* st = (unsigned short*)stage;
        for (int e = e0 + tid * 4; e + 4 <= e1; e += 512 * 4) {
            int4 d4 = *(const int4*)(dst + e);
            int dv[4] = {d4.x, d4.y, d4.z, d4.w};
            #pragma unroll
            for (int k = 0; k < 4; ++k) {
                unsigned p = atomicAdd(&rcur4[rep][dv[k] >> BSH], 1u);
                st[p] = (unsigned short)(dv[k] & (NPB - 1));
            }
        }
        for (int e = efull + tid; e < e1; e += 512) {
            int d2 = dst[e];
            unsigned p = atomicAdd(&rcur4[rep][d2 >> BSH], 1u);
            st[p] = (unsigned short)(d2 & (NPB - 1));
        }
        __syncthreads();
        unsigned short* db = dbins + (size_t)g * nbkt * NBB * SLOT;
        unsigned* cdp = cnt_d + (size_t)g * nbkt * NBB;
        for (int q = wv; q < nbkt; q += 8) {
            unsigned cd = min(hist[q], (unsigned)SLOT);
            unsigned od = offs[q];
            unsigned short* ddp = db + ((size_t)q * NBB + b) * SLOT;
            for (unsigned i = lane; i < cd; i += 64) ddp[i] = st[od + i];
            if (lane == 0) cdp[q * NBB + b] = cd;
        }
    }
}

// deg partial: 256 thr, 4 replicas, ITN unconditional loads, predicated atomics.
__global__ __launch_bounds__(256) void deg_part(
        const unsigned short* __restrict__ dbins, const unsigned* __restrict__ cnt_d,
        float* __restrict__ partials, int nbkt) {
    const int s = blockIdx.x, q = blockIdx.y, g = blockIdx.z;
    const unsigned short* dq = dbins + ((size_t)(g * nbkt + q) * NBB + s * CPS) * SLOT;
    const unsigned* cq = cnt_d + (size_t)(g * nbkt + q) * NBB + s * CPS;
    const int tid = threadIdx.x, wv = tid >> 6;
    __shared__ float bl[4][NPB];
    __shared__ unsigned lcnt[CPS];
    if (tid < CPS) lcnt[tid] = cq[tid];
    for (int i = tid; i < 4 * NPB; i += 256) ((float*)bl)[i] = 0.f;
    __syncthreads();
    float* mybl = bl[wv];
    const ushort4* d4 = (const ushort4*)dq;
    ushort4 v[ITN]; int limv[ITN];
    #pragma unroll
    for (int it = 0; it < ITN; ++it) v[it] = d4[it * 256 + tid];    // unconditional
    #pragma unroll
    for (int it = 0; it < ITN; ++it) {
        int i = it * 256 + tid;
        limv[it] = (int)lcnt[i >> 5] - ((i & 31) << 2);
    }
    #pragma unroll
    for (int it = 0; it < ITN; ++it) {
        if (limv[it] > 0) atomicAdd(&mybl[v[it].x & 511], 1.f);
        if (limv[it] > 1) atomicAdd(&mybl[v[it].y & 511], 1.f);
        if (limv[it] > 2) atomicAdd(&mybl[v[it].z & 511], 1.f);
        if (limv[it] > 3) atomicAdd(&mybl[v[it].w & 511], 1.f);
    }
    __syncthreads();
    float* pp = partials + (((size_t)(g * nbkt + q)) * SB + s) * NPB;
    for (int i = tid; i < NPB; i += 256)
        pp[i] = bl[0][i] + bl[1][i] + bl[2][i] + bl[3][i];
}

// deg combine: inv = 1/max(deg,1); block (0,0) zeroes sums+fpart2.
__global__ __launch_bounds__(512) void deg_combine(
        const float* __restrict__ partials, float* __restrict__ inv,
        float* __restrict__ zbase, int zcount, int N, int nbkt) {
    const int q = blockIdx.x, g = blockIdx.y;
    const int tid = threadIdx.x;
    if (q == 0 && g == 0)
        for (int i = tid; i < zcount; i += 512) zbase[i] = 0.f;
    const float* pp = partials + ((size_t)(g * nbkt + q)) * SB * NPB;
    float t = 0.f;
    #pragma unroll
    for (int s = 0; s < SB; ++s) t += pp[s * NPB + tid];
    const int node = q * NPB + tid;
    if (node < N) inv[(size_t)g * N + node] = 1.0f / fmaxf(t, 1.0f);
}

// prop partial: ITN unconditional slot loads, clamped gather indices,
// predicated LDS atomics.
__global__ __launch_bounds__(256) void part_scan(
        const int* __restrict__ sbins, const unsigned* __restrict__ cnt_s,
        const float* __restrict__ w, float* __restrict__ partials,
        int N, int nbkt) {
    const int s = blockIdx.x, q = blockIdx.y, g = blockIdx.z;
    const int* sq = sbins + ((size_t)(g * nbkt + q) * NBB + s * CPS) * SLOT;
    const unsigned* cq = cnt_s + (size_t)(g * nbkt + q) * NBB + s * CPS;
    const float* wg = w + (size_t)g * N;
    const int tid = threadIdx.x, wv = tid >> 6;
    __shared__ float bl[4][NPB];
    __shared__ unsigned lcnt[CPS];
    if (tid < CPS) lcnt[tid] = cq[tid];
    for (int i = tid; i < 4 * NPB; i += 256) ((float*)bl)[i] = 0.f;
    __syncthreads();
    float* mybl = bl[wv];
    const int4* s4 = (const int4*)sq;
    int4 v[ITN]; int limv[ITN];
    #pragma unroll
    for (int it = 0; it < ITN; ++it) v[it] = s4[it * 256 + tid];    // unconditional
    #pragma unroll
    for (int it = 0; it < ITN; ++it) {
        int i = it * 256 + tid;
        limv[it] = (int)lcnt[i >> 5] - ((i & 31) << 2);
    }
    float va[ITN][4];
    #pragma unroll
    for (int it = 0; it < ITN; ++it) {  // branch-free, garbage idx clamped to 0
        int i0 = (limv[it] > 0) ? (v[it].x & 0x1FFFF) : 0;
        int i1 = (limv[it] > 1) ? (v[it].y & 0x1FFFF) : 0;
        int i2 = (limv[it] > 2) ? (v[it].z & 0x1FFFF) : 0;
        int i3 = (limv[it] > 3) ? (v[it].w & 0x1FFFF) : 0;
        va[it][0] = wg[i0];
        va[it][1] = wg[i1];
        va[it][2] = wg[i2];
        va[it][3] = wg[i3];
    }
    #pragma unroll
    for (int it = 0; it < ITN; ++it) {
        if (limv[it] > 0) atomicAdd(&mybl[(((unsigned)v[it].x) >> 17) & 511], va[it][0]);
        if (limv[it] > 1) atomicAdd(&mybl[(((unsigned)v[it].y) >> 17) & 511], va[it][1]);
        if (limv[it] > 2) atomicAdd(&mybl[(((unsigned)v[it].z) >> 17) & 511], va[it][2]);
        if (limv[it] > 3) atomicAdd(&mybl[(((unsigned)v[it].w) >> 17) & 511], va[it][3]);
    }
    __syncthreads();
    float* pp = partials + (((size_t)(g * nbkt + q)) * SB + s) * NPB;
    for (int i = tid; i < NPB; i += 256)
        pp[i] = bl[0][i] + bl[1][i] + bl[2][i] + bl[3][i];
}

// prop combine: u = scale * sum_s partials; out_w = u*inv; Σu via shfl.
__global__ __launch_bounds__(512) void prop_combine(
        const float* __restrict__ partials, const float* __restrict__ inv,
        float* __restrict__ out_w, float* __restrict__ sums, int s_idx,
        int N, int nbkt, float scale) {
    const int q = blockIdx.x, g = blockIdx.y;
    const int tid = threadIdx.x, wv = tid >> 6, lane = tid & 63;
    const float* pp = partials + ((size_t)(g * nbkt + q)) * SB * NPB;
    float t = 0.f;
    #pragma unroll
    for (int s = 0; s < SB; ++s) t += pp[s * NPB + tid];
    const float u = t * scale;
    const int node = q * NPB + tid;
    const bool valid = node < N;
    if (valid) {
        size_t off = (size_t)g * N + node;
        out_w[off] = u * inv[off];
    }
    float r = valid ? u : 0.f;
    #pragma unroll
    for (int off = 32; off > 0; off >>= 1) r += __shfl_down(r, off);
    __shared__ float wsum[8];
    if (lane == 0) wsum[wv] = r;
    __syncthreads();
    if (tid == 0) {
        float s = wsum[0] + wsum[1] + wsum[2] + wsum[3]
                + wsum[4] + wsum[5] + wsum[6] + wsum[7];
        if (s != 0.f) atomicAdd(&sums[g * 2 + s_idx], s);
    }
}

// pass-3 combine + featsum, float4: block (r,q,g) handles 64 rows.
__global__ __launch_bounds__(512) void feat_combine(
        const float* __restrict__ partials,
        const float* __restrict__ feat_p, const float* __restrict__ feat_s,
        float* __restrict__ fpart2, int N, int nbkt) {
    const int r = blockIdx.x, q = blockIdx.y, g = blockIdx.z;
    const int tid = threadIdx.x;
    const int base = q * NPB + r * 64;
    __shared__ float tmp[SB][64];
    __shared__ float red[64];
    __shared__ float4 sm4[512];
    const float* pp = partials + ((size_t)(g * nbkt + q)) * SB * NPB + r * 64;
    for (int ss = tid >> 6; ss < SB; ss += 8)
        tmp[ss][tid & 63] = pp[(size_t)ss * NPB + (tid & 63)];
    __syncthreads();
    if (tid < 64) {
        float t = 0.f;
        #pragma unroll
        for (int s = 0; s < SB; ++s) t += tmp[s][tid];
        red[tid] = (base + tid < N) ? t : 0.f;
    }
    __syncthreads();
    const float* feat = g ? feat_s : feat_p;
    const float4* f4 = (const float4*)feat;
    const int col4 = tid & 31, rg = tid >> 5;   // 16 row-groups x 4 rows
    float4 acc = make_float4(0.f, 0.f, 0.f, 0.f);
    #pragma unroll
    for (int k = 0; k < 4; ++k) {
        int row = rg * 4 + k;
        if (base + row < N) {
            float uu = red[row];
            float4 fv = f4[(size_t)(base + row) * 32 + col4];
            acc.x += uu * fv.x; acc.y += uu * fv.y;
            acc.z += uu * fv.z; acc.w += uu * fv.w;
        }
    }
    sm4[tid] = acc;
    __syncthreads();
    for (int st = 8; st > 0; st >>= 1) {
        if (rg < st) {
            float4 o = sm4[(rg + st) * 32 + col4];
            float4 a = sm4[rg * 32 + col4];
            a.x += o.x; a.y += o.y; a.z += o.z; a.w += o.w;
            sm4[rg * 32 + col4] = a;
        }
        __syncthreads();
    }
    if (tid < 32) {
        float4 t = sm4[tid];
        float* dstp = fpart2 + ((size_t)g * 32 + ((q * 8 + r) & 31)) * D + tid * 4;
        atomicAdd(dstp + 0, t.x);
        atomicAdd(dstp + 1, t.y);
        atomicAdd(dstp + 2, t.z);
        atomicAdd(dstp + 3, t.w);
    }
}

// weight pre-collapse: T0 = W1@W2 (blocks 0..63), Av = (b0@W1)@W2 (block 64),
// Bv = b1@W2 (block 65).
__global__ __launch_bounds__(256) void wprep(
        const float* __restrict__ W1, const float* __restrict__ W2,
        const float* __restrict__ b0, const float* __restrict__ b1,
        float* __restrict__ T0, float* __restrict__ Av, float* __restrict__ Bv) {
    const int b = blockIdx.x, tid = threadIdx.x;
    if (b < 64) {
        const int row = 2 * b + (tid >> 7), col = tid & 127;
        float acc = 0.f;
        const float* w1r = W1 + (size_t)row * 128;
        #pragma unroll 8
        for (int k = 0; k < 128; ++k) acc += w1r[k] * W2[(size_t)k * 128 + col];
        T0[(size_t)row * 128 + col] = acc;
    } else if (b == 64) {
        __shared__ float bv[128];
        if (tid < 128) {
            float a = 0.f;
            #pragma unroll 8
            for (int i = 0; i < 128; ++i) a += b0[i] * W1[(size_t)i * 128 + tid];
            bv[tid] = a;
        }
        __syncthreads();
        if (tid < 128) {
            float a = 0.f;
            #pragma unroll 8
            for (int i = 0; i < 128; ++i) a += bv[i] * W2[(size_t)i * 128 + tid];
            Av[tid] = a;
        }
    } else {
        if (tid < 128) {
            float a = 0.f;
            #pragma unroll 8
            for (int i = 0; i < 128; ++i) a += b1[i] * W2[(size_t)i * 128 + tid];
            Bv[tid] = a;
        }
    }
}

// 1024 threads: parallel per-graph chains using precomputed T0/Av/Bv.
__global__ __launch_bounds__(1024) void final_kernel(
        const float* __restrict__ fpart2, const float* __restrict__ sums,
        const float* __restrict__ W0, const float* __restrict__ T0,
        const float* __restrict__ Av, const float* __restrict__ Bv,
        const float* __restrict__ b2,
        const float* __restrict__ Wr, const float* __restrict__ br,
        const float* __restrict__ Wm1, const float* __restrict__ bm1,
        const float* __restrict__ Wm2, const float* __restrict__ bm2,
        float* __restrict__ out) {
    __shared__ float x[2][128];
    __shared__ float part[2][4][128];
    __shared__ float rvec[256];
    __shared__ float gv[256];
    __shared__ float m1[128];
    const int tid = threadIdx.x;
    const int j = tid & 127;
    const int h = (tid >> 7) & 3;
    const int gg = tid >> 9;

    auto mv128 = [&](const float* __restrict__ W, float* __restrict__ buf) {
        float p = 0.f;
        const float* Wp = W + (size_t)(h * 32) * 128 + j;
        #pragma unroll
        for (int i = 0; i < 32; ++i) p += buf[h * 32 + i] * Wp[(size_t)i * 128];
        part[gg][h][j] = p;
        __syncthreads();
        if (h == 0)
            buf[j] = part[gg][0][j] + part[gg][1][j] + part[gg][2][j] + part[gg][3][j];
        __syncthreads();
    };

    if (tid < 256) {
        int g = tid >> 7;
        const float* fp = fpart2 + (size_t)g * 4096 + (tid & 127);
        float rv = 0.f;
        #pragma unroll
        for (int b = 0; b < 32; ++b) rv += fp[(size_t)b * 128];
        rvec[tid] = rv;
    }
    __syncthreads();

    {
        const float s1 = sums[gg * 2 + 0];
        const float s2 = sums[gg * 2 + 1];
        if (h == 0) x[gg][j] = rvec[gg * 128 + j];
        __syncthreads();
        mv128(W0, x[gg]);
        mv128(T0, x[gg]);
        if (h == 0) x[gg][j] += s2 * Av[j] + s1 * Bv[j] + b2[j];
        __syncthreads();
        mv128(Wr, x[gg]);
        if (h == 0) gv[gg * 128 + j] = 1.0f / (1.0f + expf(-(x[gg][j] + br[j])));
        __syncthreads();
    }

    {
        float p = 0.f;
        const float* Wp = Wm1 + (size_t)(h * 64) * 128 + j;
        #pragma unroll
        for (int i = 0; i < 64; ++i) p += gv[h * 64 + i] * Wp[(size_t)i * 128];
        part[gg][h][j] = p;
        __syncthreads();
        if (tid < 128)
            m1[j] = (part[0][0][j] + part[0][1][j] + part[0][2][j] + part[0][3][j]
                     + bm1[j]) * Wm2[j];
        __syncthreads();
        if (tid < 64) m1[tid] += m1[tid + 64];
        __syncthreads();
        if (tid < 32) m1[tid] += m1[tid + 32];
        __syncthreads();
        if (tid < 16) m1[tid] += m1[tid + 16];
        __syncthreads();
        if (tid < 8) m1[tid] += m1[tid + 8];
        __syncthreads();
        if (tid < 4) m1[tid] += m1[tid + 4];
        __syncthreads();
        if (tid < 2) m1[tid] += m1[tid + 2];
        __syncthreads();
        if (tid == 0) out[0] = 1.0f / (1.0f + expf(-(m1[0] + m1[1] + bm2[0])));
    }
}

extern "C" void kernel_launch(void* const* d_in, const int* in_sizes, int n_in,
                              void* d_out, int out_size, void* d_ws, size_t ws_size,
                              hipStream_t stream) {
    const float* feat_p = (const float*)d_in[0];
    const int*   src_p  = (const int*)d_in[1];
    const int*   dst_p  = (const int*)d_in[2];
    const float* feat_s = (const float*)d_in[3];
    const int*   src_s  = (const int*)d_in[4];
    const int*   dst_s  = (const int*)d_in[5];
    const float* W0 = (const float*)d_in[6];
    const float* b0 = (const float*)d_in[7];
    const float* W1 = (const float*)d_in[8];
    const float* b1 = (const float*)d_in[9];
    const float* W2 = (const float*)d_in[10];
    const float* b2 = (const float*)d_in[11];
    const float* Wr = (const float*)d_in[12];
    const float* br = (const float*)d_in[13];
    const float* Wm1 = (const float*)d_in[14];
    const float* bm1 = (const float*)d_in[15];
    const float* Wm2 = (const float*)d_in[16];
    const float* bm2 = (const float*)d_in[17];
    float* out = (float*)d_out;

    const int N = in_sizes[0] / D;   // 50000
    const int E = in_sizes[1];       // 1600000
    const int N2 = 2 * N;
    const int nbkt = (N + NPB - 1) >> BSH;   // 98

    // ws (floats): sums[16] | fpart2[2*32*128] | T0[16384] | Av[128] | Bv[128] |
    //   inv[2N] | w1[2N] | w2[2N] | partials[2*nbkt*SB*NPB] |
    //   cnt_s[2*nbkt*NBB u32] | cnt_d | sbins[2*nbkt*NBB*SLOT int] | dbins[ushort]
    float* ws     = (float*)d_ws;
    float* sums   = ws;
    float* fpart2 = ws + 16;
    float* T0     = fpart2 + 2 * 32 * 128;
    float* Av     = T0 + 128 * 128;
    float* Bv     = Av + 128;
    float* inv    = Bv + 128;
    float* w1     = inv + N2;
    float* w2     = w1 + N2;
    float* partials = w2 + N2;
    unsigned* cnt_s = (unsigned*)(partials + (size_t)2 * nbkt * SB * NPB);
    unsigned* cnt_d = cnt_s + (size_t)2 * nbkt * NBB;
    int* sbins    = (int*)(cnt_d + (size_t)2 * nbkt * NBB);
    unsigned short* dbins = (unsigned short*)(sbins + (size_t)2 * nbkt * NBB * SLOT);

    const float u0 = 1.0f / (float)N;
    const int zcount = 16 + 2 * 32 * 128;    // sums + fpart2 (zeroed in deg_combine)

    wprep<<<66, 256, 0, stream>>>(W1, W2, b0, b1, T0, Av, Bv);

    bin_kernel<<<dim3(NBB, 2, 2), 512, 0, stream>>>(src_p, dst_p, src_s, dst_s,
                                                    sbins, dbins, cnt_s, cnt_d,
                                                    E, nbkt);

    deg_part<<<dim3(SB, nbkt, 2), 256, 0, stream>>>(dbins, cnt_d, partials, nbkt);
    deg_combine<<<dim3(nbkt, 2), 512, 0, stream>>>(partials, inv, ws, zcount,
                                                   N, nbkt);

    part_scan<<<dim3(SB, nbkt, 2), 256, 0, stream>>>(sbins, cnt_s, inv,
                                                     partials, N, nbkt);
    prop_combine<<<dim3(nbkt, 2), 512, 0, stream>>>(partials, inv, w1,
                                                    sums, 0, N, nbkt, u0);

    part_scan<<<dim3(SB, nbkt, 2), 256, 0, stream>>>(sbins, cnt_s, w1,
                                                     partials, N, nbkt);
    prop_combine<<<dim3(nbkt, 2), 512, 0, stream>>>(partials, inv, w2,
                                                    sums, 1, N, nbkt, 1.0f);

    part_scan<<<dim3(SB, nbkt, 2), 256, 0, stream>>>(sbins, cnt_s, w2,
                                                     partials, N, nbkt);
    feat_combine<<<dim3(8, nbkt, 2), 512, 0, stream>>>(partials, feat_p, feat_s,
                                                       fpart2, N, nbkt);

    final_kernel<<<1, 1024, 0, stream>>>(fpart2, sums, W0, T0, Av, Bv, b2,
                                         Wr, br, Wm1, bm1, Wm2, bm2, out);
}